// Round 9
// baseline (813.690 us; speedup 1.0000x reference)
//
#include <hip/hip_runtime.h>
#include <hip/hip_bf16.h>

// Problem constants (B=4, T=2048, D=1024, H=16, HD=64)
constexpr int NB  = 4;
constexpr int NT  = 2048;
constexpr int ND  = 1024;
constexpr int NH  = 16;
constexpr int NHD = 64;
constexpr int NM  = NB * NT;   // 8192 tokens

typedef unsigned short u16;
typedef __attribute__((ext_vector_type(8))) short  short8;  // 8 bf16 (4 VGPRs)
typedef __attribute__((ext_vector_type(4))) float  f32x4;   // MFMA acc

__device__ __forceinline__ u16 f2bf(float f) {
  unsigned u = __builtin_bit_cast(unsigned, f);
  u += 0x7FFFu + ((u >> 16) & 1u);   // round-to-nearest-even
  return (u16)(u >> 16);
}

// pack two f32 -> 2x bf16 in one dword (compiler emits v_cvt_pk_bf16_f32)
__device__ __forceinline__ unsigned pk2bf(float lo, float hi_) {
  float2 t; t.x = lo; t.y = hi_;
  __hip_bfloat162 h2 = __float22bfloat162_rn(t);
  unsigned u;
  __builtin_memcpy(&u, &h2, 4);
  return u;
}

// ---------------- cast f32 -> bf16, vectorized x4 ----------------
__global__ __launch_bounds__(256) void cast_kernel(const float* __restrict__ in,
                                                   u16* __restrict__ out, int n4) {
  int i = blockIdx.x * 256 + threadIdx.x;
  if (i >= n4) return;
  float4 v = ((const float4*)in)[i];
  ushort4 o;
  o.x = f2bf(v.x); o.y = f2bf(v.y); o.z = f2bf(v.z); o.w = f2bf(v.w);
  ((ushort4*)out)[i] = o;
}

// cast all 4 weight matrices in one launch (1024 blocks each)
__global__ __launch_bounds__(256) void cast4_kernel(
    const float* __restrict__ w0, const float* __restrict__ w1,
    const float* __restrict__ w2, const float* __restrict__ w3,
    u16* __restrict__ o0, u16* __restrict__ o1,
    u16* __restrict__ o2, u16* __restrict__ o3) {
  const int z = blockIdx.x >> 10;
  const float* in = (z == 0) ? w0 : (z == 1) ? w1 : (z == 2) ? w2 : w3;
  u16* out       = (z == 0) ? o0 : (z == 1) ? o1 : (z == 2) ? o2 : o3;
  int i = (blockIdx.x & 1023) * 256 + threadIdx.x;
  float4 v = ((const float4*)in)[i];
  ushort4 o;
  o.x = f2bf(v.x); o.y = f2bf(v.y); o.z = f2bf(v.z); o.w = f2bf(v.w);
  ((ushort4*)out)[i] = o;
}

// ---------------- QKV GEMM: y = x @ W^T ----------------
// BK=64 tiles ([128][64] u16 = 128B rows), XOR chunk-swizzle (conflict-free, r7: 0).
// T14 reg-staged pipeline: load tile k+1 to regs BEFORE computing tile k, ds_write
// after the barrier -> global latency hides under MFMA+ds_read (r8 structure exposed
// full latency: gll16 issued right before a vmcnt(0)-draining barrier).
// NATURAL grid mapping (r6: 49 MB fetch vs 200 MB with chunked remap — keep natural).
__global__ __launch_bounds__(256, 3) void gemm_qkv(
    const u16* __restrict__ xb,
    const u16* __restrict__ wqb, const u16* __restrict__ wkb, const u16* __restrict__ wvb,
    u16* __restrict__ Qb, u16* __restrict__ Kb, u16* __restrict__ VTb) {
  const int z    = blockIdx.z;
  const int row0 = blockIdx.x << 7;
  const int col0 = blockIdx.y << 7;

  const u16* wsel = (z == 0) ? wqb : (z == 1) ? wkb : wvb;
  u16* osel      = (z == 0) ? Qb  : (z == 1) ? Kb  : VTb;
  // attention scale + log2(e) folded into Q (softmax done in exp2 domain)
  const float scl = (z == 0) ? 0.125f * 1.44269504f : 1.0f;

  const int tid  = threadIdx.x;
  const int lane = tid & 63, wid = tid >> 6;
  const int wm = wid >> 1, wn = wid & 1;
  const int li = lane & 15, hi = lane >> 4;

  __shared__ __align__(16) u16 lA[128 * 64];
  __shared__ __align__(16) u16 lB[128 * 64];

  // staging geometry: [128 rows][8 slots of 16B]; thread owns rows h*32+srow, slot dsl.
  // LDS holds global chunk (dsl ^ (row&7)) at slot dsl (same placement as r8 -> reads unchanged)
  const int srow = tid >> 3;          // 0..31
  const int dsl  = tid & 7;
  const int ssl  = dsl ^ (srow & 7);  // (h*32 doesn't change row&7)

  uint4 rA[4], rB[4];
  auto issue = [&](int k0) {
#pragma unroll
    for (int h = 0; h < 4; ++h) {
      rA[h] = *(const uint4*)&xb  [(size_t)(row0 + h * 32 + srow) * ND + k0 + ssl * 8];
      rB[h] = *(const uint4*)&wsel[(size_t)(col0 + h * 32 + srow) * ND + k0 + ssl * 8];
    }
  };
  auto commit = [&]() {
#pragma unroll
    for (int h = 0; h < 4; ++h) {
      *(uint4*)&lA[(h * 32 + srow) * 64 + dsl * 8] = rA[h];
      *(uint4*)&lB[(h * 32 + srow) * 64 + dsl * 8] = rB[h];
    }
  };

  f32x4 acc[4][4] = {};

  issue(0);
  commit();
  __syncthreads();

  for (int k0 = 0;;) {
    const int nk = k0 + 64;
    if (nk < ND) issue(nk);        // prefetch in flight under compute below

    short8 a[4][2], b[4][2];
#pragma unroll
    for (int m = 0; m < 4; ++m)
#pragma unroll
      for (int c = 0; c < 2; ++c)
        a[m][c] = *(const short8*)&lA[(wm * 64 + m * 16 + li) * 64 + (((c * 4 + hi) ^ (li & 7)) << 3)];
#pragma unroll
    for (int n = 0; n < 4; ++n)
#pragma unroll
      for (int c = 0; c < 2; ++c)
        b[n][c] = *(const short8*)&lB[(wn * 64 + n * 16 + li) * 64 + (((c * 4 + hi) ^ (li & 7)) << 3)];
    if (z == 2) {
#pragma unroll
      for (int m = 0; m < 4; ++m)
#pragma unroll
        for (int n = 0; n < 4; ++n)
#pragma unroll
          for (int c = 0; c < 2; ++c)
            acc[m][n] = __builtin_amdgcn_mfma_f32_16x16x32_bf16(a[m][c], b[n][c], acc[m][n], 0, 0, 0);
    } else {  // swapped: acc = C^T fragment (row=feature, col=token)
#pragma unroll
      for (int m = 0; m < 4; ++m)
#pragma unroll
        for (int n = 0; n < 4; ++n)
#pragma unroll
          for (int c = 0; c < 2; ++c)
            acc[m][n] = __builtin_amdgcn_mfma_f32_16x16x32_bf16(b[n][c], a[m][c], acc[m][n], 0, 0, 0);
    }

    k0 = nk;
    if (k0 >= ND) break;
    __syncthreads();               // all waves done reading current tile
    commit();                      // write prefetched tile (vmcnt waited here, latency covered)
    __syncthreads();               // tile ready
  }

#pragma unroll
  for (int m = 0; m < 4; ++m)
#pragma unroll
    for (int n = 0; n < 4; ++n) {
      if (z == 2) {
        // normal: row=token(hi*4+rg), col=feature(li). Pack 4 consecutive t.
        int token0 = row0 + wm * 64 + m * 16 + hi * 4;
        int col    = col0 + wn * 64 + n * 16 + li;
        int b_ = token0 >> 11, t0 = token0 & (NT - 1);
        int h_ = col >> 6,     d_ = col & (NHD - 1);
        uint2 w;
        w.x = pk2bf(acc[m][n][0], acc[m][n][1]);
        w.y = pk2bf(acc[m][n][2], acc[m][n][3]);
        *(uint2*)&osel[(((size_t)(b_ * NH + h_)) * NHD + d_) * NT + t0] = w;
      } else {
        // swapped: row=feature(hi*4+rg), col=token(li). Pack 4 consecutive d.
        int token = row0 + wm * 64 + m * 16 + li;
        int feat0 = col0 + wn * 64 + n * 16 + hi * 4;
        int b_ = token >> 11, t_ = token & (NT - 1);
        int h_ = feat0 >> 6,  d0 = feat0 & (NHD - 1);
        uint2 w;
        w.x = pk2bf(acc[m][n][0] * scl, acc[m][n][1] * scl);
        w.y = pk2bf(acc[m][n][2] * scl, acc[m][n][3] * scl);
        *(uint2*)&osel[(((size_t)(b_ * NH + h_)) * NT + t_) * NHD + d0] = w;
      }
    }
}

// ---------------- WO GEMM + residual: out = x + AO @ WO^T (f32 out) ----------------
// Same T14 reg-staged pipeline; swapped orientation -> float4 load/store epilogue.
__global__ __launch_bounds__(256, 3) void gemm_wo(
    const u16* __restrict__ ao, const u16* __restrict__ wob,
    const float* __restrict__ x, float* __restrict__ y) {
  const int row0 = blockIdx.x << 7;
  const int col0 = blockIdx.y << 7;

  const int tid  = threadIdx.x;
  const int lane = tid & 63, wid = tid >> 6;
  const int wm = wid >> 1, wn = wid & 1;
  const int li = lane & 15, hi = lane >> 4;

  __shared__ __align__(16) u16 lA[128 * 64];
  __shared__ __align__(16) u16 lB[128 * 64];

  const int srow = tid >> 3;
  const int dsl  = tid & 7;
  const int ssl  = dsl ^ (srow & 7);

  uint4 rA[4], rB[4];
  auto issue = [&](int k0) {
#pragma unroll
    for (int h = 0; h < 4; ++h) {
      rA[h] = *(const uint4*)&ao [(size_t)(row0 + h * 32 + srow) * ND + k0 + ssl * 8];
      rB[h] = *(const uint4*)&wob[(size_t)(col0 + h * 32 + srow) * ND + k0 + ssl * 8];
    }
  };
  auto commit = [&]() {
#pragma unroll
    for (int h = 0; h < 4; ++h) {
      *(uint4*)&lA[(h * 32 + srow) * 64 + dsl * 8] = rA[h];
      *(uint4*)&lB[(h * 32 + srow) * 64 + dsl * 8] = rB[h];
    }
  };

  f32x4 acc[4][4] = {};

  issue(0);
  commit();
  __syncthreads();

  for (int k0 = 0;;) {
    const int nk = k0 + 64;
    if (nk < ND) issue(nk);

    short8 a[4][2], b[4][2];
#pragma unroll
    for (int m = 0; m < 4; ++m)
#pragma unroll
      for (int c = 0; c < 2; ++c)
        a[m][c] = *(const short8*)&lA[(wm * 64 + m * 16 + li) * 64 + (((c * 4 + hi) ^ (li & 7)) << 3)];
#pragma unroll
    for (int n = 0; n < 4; ++n)
#pragma unroll
      for (int c = 0; c < 2; ++c)
        b[n][c] = *(const short8*)&lB[(wn * 64 + n * 16 + li) * 64 + (((c * 4 + hi) ^ (li & 7)) << 3)];
#pragma unroll
    for (int m = 0; m < 4; ++m)
#pragma unroll
      for (int n = 0; n < 4; ++n)
#pragma unroll
        for (int c = 0; c < 2; ++c)
          acc[m][n] = __builtin_amdgcn_mfma_f32_16x16x32_bf16(b[n][c], a[m][c], acc[m][n], 0, 0, 0);

    k0 = nk;
    if (k0 >= ND) break;
    __syncthreads();
    commit();
    __syncthreads();
  }

#pragma unroll
  for (int m = 0; m < 4; ++m)
#pragma unroll
    for (int n = 0; n < 4; ++n) {
      int token = row0 + wm * 64 + m * 16 + li;
      int feat0 = col0 + wn * 64 + n * 16 + hi * 4;
      size_t idx = (size_t)token * ND + feat0;
      float4 xv = *(const float4*)&x[idx];
      float4 o;
      o.x = acc[m][n][0] + xv.x; o.y = acc[m][n][1] + xv.y;
      o.z = acc[m][n][2] + xv.z; o.w = acc[m][n][3] + xv.w;
      *(float4*)&y[idx] = o;
    }
}

// ---------------- causal flash attention (static-max softmax) ----------------
// grid 2048, XCD-swizzled + heavy-first. 4 waves; wave owns 16 q-rows.
// STATIC-MAX: P = exp2(S) with NO running max / rescale. Scores are bounded
// (|S|*log2e << 126) and bf16/f32 share the 8-bit exponent, so numerator and
// denominator carry the scale exactly; one divide at the end normalizes.
// Deletes 15 fmax + 2 serial shuffles + defer branch + 16 subs per tile (VALU was 51%).
__global__ __launch_bounds__(256) void attn_kernel(
    const u16* __restrict__ Q, const u16* __restrict__ K, const u16* __restrict__ VT,
    u16* __restrict__ AO) {
  // T1: XCD-aware swizzle (2048 % 8 == 0 -> bijective)
  const int nb  = gridDim.x * gridDim.y;           // 2048
  const int b0  = blockIdx.y * gridDim.x + blockIdx.x;
  const int L   = (b0 & 7) * (nb >> 3) + (b0 >> 3);
  const int qb  = 31 - (L & 31);     // heavy-first: big qb dispatched early
  const int bh  = L >> 5;            // 0..63

  const int tid = threadIdx.x;
  const int lane = tid & 63, wid = tid >> 6;
  const int li = lane & 15, hi = lane >> 4;
  const int r0 = qb * 64 + wid * 16;         // wave's q rows
  const int qrow = r0 + li;                  // this lane's q row
  const size_t bK = (size_t)bh * NT * NHD;   // K  [bh][t][d]
  const size_t bV = (size_t)bh * NHD * NT;   // VT [bh][d][t]

  __shared__ __align__(16) u16 lK [2][64 * 64];
  __shared__ __align__(16) u16 lVT[2][64 * 64];
  __shared__ __align__(16) u16 lP [4][16 * 64];

  // ---- reg-staging geometry: 512 chunks of 8 u16 per tile; thread owns ch0=tid, ch1=tid+256
  const int ch0 = tid, ch1 = tid + 256;
  const int d0 = (ch0 >> 3) * 64 + (((ch0 & 7) ^ ((ch0 >> 3) & 7)) << 3);
  const int d1 = (ch1 >> 3) * 64 + (((ch1 & 7) ^ ((ch1 >> 3) & 7)) << 3);
  const int vOff0 = (ch0 >> 3) * NT + (ch0 & 7) * 8;
  const int vOff1 = (ch1 >> 3) * NT + (ch1 & 7) * 8;

  uint4 gK0, gK1, gV0, gV1;
  auto issue = [&](int kt) {
    const u16* kp = K + bK + (size_t)kt * 4096;
    const u16* vp = VT + bV + kt * 64;
    gK0 = *(const uint4*)&kp[ch0 * 8];
    gK1 = *(const uint4*)&kp[ch1 * 8];
    gV0 = *(const uint4*)&vp[vOff0];
    gV1 = *(const uint4*)&vp[vOff1];
  };
  auto commit = [&](int buf) {
    *(uint4*)&lK [buf][d0] = gK0;
    *(uint4*)&lK [buf][d1] = gK1;
    *(uint4*)&lVT[buf][d0] = gV0;
    *(uint4*)&lVT[buf][d1] = gV1;
  };

  // Q fragments (B-operand): lane holds Q[qrow][c*32 + hi*8 + e]
  short8 qf[2];
#pragma unroll
  for (int c = 0; c < 2; ++c)
    qf[c] = *(const short8*)&Q[bK + (size_t)qrow * NHD + c * 32 + hi * 8];

  short8 vone;
#pragma unroll
  for (int e = 0; e < 8; ++e) vone[e] = (short)0x3F80;   // bf16 1.0

  f32x4 o[4] = {};
  f32x4 o4 = {};          // rowsum accumulator (all 4 regs equal)

  issue(0);
  commit(0);
  __syncthreads();
  int buf = 0;

  const int pswz = (li & 7) << 1;   // P-LDS XOR swizzle (8B chunks, bit0 preserved)

  for (int kt = 0; kt <= qb; ++kt) {
    if (kt < qb) issue(kt + 1);    // loads in flight under the compute below

    // S^T = K Q^T : s[g][rg] = S[q=li][k = g*16 + hi*4 + rg]
    f32x4 s[4] = {};
    __builtin_amdgcn_s_setprio(1);
#pragma unroll
    for (int g = 0; g < 4; ++g)
#pragma unroll
      for (int c = 0; c < 2; ++c) {
        short8 kf = *(const short8*)&lK[buf][(g * 16 + li) * 64 + ((c * 4 + hi) ^ (li & 7)) * 8];
        s[g] = __builtin_amdgcn_mfma_f32_16x16x32_bf16(kf, qf[c], s[g], 0, 0, 0);
      }
    __builtin_amdgcn_s_setprio(0);

    if (kt == qb) {                          // causal mask on diagonal tile
#pragma unroll
      for (int g = 0; g < 4; ++g)
#pragma unroll
        for (int rg = 0; rg < 4; ++rg) {
          int kcol = kt * 64 + g * 16 + hi * 4 + rg;
          if (kcol > qrow) s[g][rg] = -INFINITY;
        }
    }

    // P = exp2(S) -> LDS as bf16 (static-max; exp2(-inf)=0 handles the mask)
#pragma unroll
    for (int g = 0; g < 4; ++g) {
      float p0 = __builtin_amdgcn_exp2f(s[g][0]);
      float p1 = __builtin_amdgcn_exp2f(s[g][1]);
      float p2 = __builtin_amdgcn_exp2f(s[g][2]);
      float p3 = __builtin_amdgcn_exp2f(s[g][3]);
      uint2 w;
      w.x = pk2bf(p0, p1);
      w.y = pk2bf(p2, p3);
      int k8s = (g * 4 + hi) ^ pswz;
      *(uint2*)&lP[wid][li * 64 + k8s * 4] = w;
    }

    // P as B-operand: lane reads P[q=li][c*32 + hi*8 .. +7]
    short8 pa[2];
#pragma unroll
    for (int c = 0; c < 2; ++c)
      pa[c] = *(const short8*)&lP[wid][li * 64 + ((c * 8 + hi * 2) ^ pswz) * 4];

    // O^T += V^T P^T ; rowsum via ones
    __builtin_amdgcn_s_setprio(1);
#pragma unroll
    for (int gd = 0; gd < 4; ++gd)
#pragma unroll
      for (int c = 0; c < 2; ++c) {
        short8 vf = *(const short8*)&lVT[buf][(gd * 16 + li) * 64 + ((c * 4 + hi) ^ (li & 7)) * 8];
        o[gd] = __builtin_amdgcn_mfma_f32_16x16x32_bf16(vf, pa[c], o[gd], 0, 0, 0);
      }
#pragma unroll
    for (int c = 0; c < 2; ++c)
      o4 = __builtin_amdgcn_mfma_f32_16x16x32_bf16(vone, pa[c], o4, 0, 0, 0);
    __builtin_amdgcn_s_setprio(0);

    if (kt < qb) commit(buf ^ 1);   // vmcnt consumed here (hidden under compute above)
    __syncthreads();                // vmcnt already 0 -> no drain stall
    buf ^= 1;
  }

  // epilogue: O /= rowsum; pack 4 bf16 (8B) per gd and store
  const int b_ = bh >> 4, h_ = bh & 15;
  const float inv = 1.0f / o4[0];
  const size_t rowbase = ((size_t)(b_ * NT + qrow)) * ND + h_ * 64;
#pragma unroll
  for (int gd = 0; gd < 4; ++gd) {
    uint2 w;
    w.x = pk2bf(o[gd][0] * inv, o[gd][1] * inv);
    w.y = pk2bf(o[gd][2] * inv, o[gd][3] * inv);
    *(uint2*)&AO[rowbase + gd * 16 + hi * 4] = w;
  }
}

// ---------------- RMSNorm in-place on d_out ----------------
__global__ __launch_bounds__(256) void rmsnorm_kernel(float* __restrict__ y,
                                                      const float* __restrict__ g) {
  const int row = blockIdx.x;
  const int tid = threadIdx.x;
  const int lane = tid & 63, wid = tid >> 6;
  float4 v = ((const float4*)(y + (size_t)row * ND))[tid];
  float ss = v.x * v.x + v.y * v.y + v.z * v.z + v.w * v.w;
#pragma unroll
  for (int off = 32; off; off >>= 1) ss += __shfl_down(ss, off);
  __shared__ float red[4];
  if (lane == 0) red[wid] = ss;
  __syncthreads();
  float tot = red[0] + red[1] + red[2] + red[3];
  float inv = rsqrtf(tot * (1.0f / (float)ND) + 1e-6f);
  float4 gg = ((const float4*)g)[tid];
  float4 o;
  o.x = v.x * inv * gg.x; o.y = v.y * inv * gg.y;
  o.z = v.z * inv * gg.z; o.w = v.w * inv * gg.w;
  ((float4*)(y + (size_t)row * ND))[tid] = o;
}

extern "C" void kernel_launch(void* const* d_in, const int* in_sizes, int n_in,
                              void* d_out, int out_size, void* d_ws, size_t ws_size,
                              hipStream_t stream) {
  const float* x  = (const float*)d_in[0];
  const float* wq = (const float*)d_in[1];
  const float* wk = (const float*)d_in[2];
  const float* wv = (const float*)d_in[3];
  const float* wo = (const float*)d_in[4];
  const float* ng = (const float*)d_in[5];
  float* out = (float*)d_out;

  char* ws = (char*)d_ws;
  u16* xb  = (u16*)(ws);                    // 16 MB  [M, D] bf16
  u16* wqb = (u16*)(ws + (16u << 20));      //  2 MB
  u16* wkb = (u16*)(ws + (18u << 20));
  u16* wvb = (u16*)(ws + (20u << 20));
  u16* wob = (u16*)(ws + (22u << 20));
  u16* Qb  = (u16*)(ws + (24u << 20));      // 16 MB  [B,H,T,HD]
  u16* Kb  = (u16*)(ws + (40u << 20));      // 16 MB  [B,H,T,HD]
  u16* VTb = (u16*)(ws + (56u << 20));      // 16 MB  [B,H,HD,T]  (transposed V)
  u16* AO  = (u16*)(ws + (72u << 20));      // 16 MB  [M, D]  (ends at 88 MB)

  cast_kernel<<<NM * ND / 4 / 256, 256, 0, stream>>>(x, xb, NM * ND / 4);
  cast4_kernel<<<4 * 1024, 256, 0, stream>>>(wq, wk, wv, wo, wqb, wkb, wvb, wob);

  gemm_qkv<<<dim3(64, 8, 3), 256, 0, stream>>>(xb, wqb, wkb, wvb, Qb, Kb, VTb);
  attn_kernel<<<dim3(NT / 64, NB * NH), 256, 0, stream>>>(Qb, Kb, VTb, AO);
  gemm_wo<<<dim3(64, 8), 256, 0, stream>>>(AO, wob, x, out);
  rmsnorm_kernel<<<NM, 256, 0, stream>>>(out, ng);
}

// Round 10
// 656.761 us; speedup vs baseline: 1.2389x; 1.2389x over previous
//
#include <hip/hip_runtime.h>
#include <hip/hip_bf16.h>

// Problem constants (B=4, T=2048, D=1024, H=16, HD=64)
constexpr int NB  = 4;
constexpr int NT  = 2048;
constexpr int ND  = 1024;
constexpr int NH  = 16;
constexpr int NHD = 64;
constexpr int NM  = NB * NT;   // 8192 tokens

typedef unsigned short u16;
typedef __attribute__((ext_vector_type(8))) short  short8;  // 8 bf16 (4 VGPRs)
typedef __attribute__((ext_vector_type(4))) float  f32x4;   // MFMA acc

__device__ __forceinline__ u16 f2bf(float f) {
  unsigned u = __builtin_bit_cast(unsigned, f);
  u += 0x7FFFu + ((u >> 16) & 1u);   // round-to-nearest-even
  return (u16)(u >> 16);
}

// pack two f32 -> 2x bf16 in one dword (compiler emits v_cvt_pk_bf16_f32)
__device__ __forceinline__ unsigned pk2bf(float lo, float hi_) {
  float2 t; t.x = lo; t.y = hi_;
  __hip_bfloat162 h2 = __float22bfloat162_rn(t);
  unsigned u;
  __builtin_memcpy(&u, &h2, 4);
  return u;
}

// ---------------- cast f32 -> bf16, vectorized x4 ----------------
__global__ __launch_bounds__(256) void cast_kernel(const float* __restrict__ in,
                                                   u16* __restrict__ out, int n4) {
  int i = blockIdx.x * 256 + threadIdx.x;
  if (i >= n4) return;
  float4 v = ((const float4*)in)[i];
  ushort4 o;
  o.x = f2bf(v.x); o.y = f2bf(v.y); o.z = f2bf(v.z); o.w = f2bf(v.w);
  ((ushort4*)out)[i] = o;
}

// cast all 4 weight matrices in one launch (1024 blocks each)
__global__ __launch_bounds__(256) void cast4_kernel(
    const float* __restrict__ w0, const float* __restrict__ w1,
    const float* __restrict__ w2, const float* __restrict__ w3,
    u16* __restrict__ o0, u16* __restrict__ o1,
    u16* __restrict__ o2, u16* __restrict__ o3) {
  const int z = blockIdx.x >> 10;
  const float* in = (z == 0) ? w0 : (z == 1) ? w1 : (z == 2) ? w2 : w3;
  u16* out       = (z == 0) ? o0 : (z == 1) ? o1 : (z == 2) ? o2 : o3;
  int i = (blockIdx.x & 1023) * 256 + threadIdx.x;
  float4 v = ((const float4*)in)[i];
  ushort4 o;
  o.x = f2bf(v.x); o.y = f2bf(v.y); o.z = f2bf(v.z); o.w = f2bf(v.w);
  ((ushort4*)out)[i] = o;
}

// ---------------- QKV GEMM: y = x @ W^T ----------------
// BK=64 tiles ([128][64] u16 = 128B rows), XOR chunk-swizzle (conflict-free, r7: 0).
// T14 reg-staged pipeline with NAMED SCALAR uint4 staging regs (r9 lesson: uint4
// ARRAYS captured in lambdas spill to scratch -> GBs of TCC traffic, 7x slowdown).
// NATURAL grid mapping (r6: 49 MB fetch vs 200 MB with chunked remap).
__global__ __launch_bounds__(256, 3) void gemm_qkv(
    const u16* __restrict__ xb,
    const u16* __restrict__ wqb, const u16* __restrict__ wkb, const u16* __restrict__ wvb,
    u16* __restrict__ Qb, u16* __restrict__ Kb, u16* __restrict__ VTb) {
  const int z    = blockIdx.z;
  const int row0 = blockIdx.x << 7;
  const int col0 = blockIdx.y << 7;

  const u16* wsel = (z == 0) ? wqb : (z == 1) ? wkb : wvb;
  u16* osel      = (z == 0) ? Qb  : (z == 1) ? Kb  : VTb;
  // attention scale + log2(e) folded into Q (softmax done in exp2 domain)
  const float scl = (z == 0) ? 0.125f * 1.44269504f : 1.0f;

  const int tid  = threadIdx.x;
  const int lane = tid & 63, wid = tid >> 6;
  const int wm = wid >> 1, wn = wid & 1;
  const int li = lane & 15, hi = lane >> 4;

  __shared__ __align__(16) u16 lA[128 * 64];
  __shared__ __align__(16) u16 lB[128 * 64];

  // staging geometry: [128 rows][8 slots of 16B]; thread owns rows h*32+srow, slot dsl.
  const int srow = tid >> 3;          // 0..31
  const int dsl  = tid & 7;
  const int ssl  = dsl ^ (srow & 7);  // source chunk for this dest slot

  const u16* pa_ = &xb  [(size_t)(row0 + srow) * ND + ssl * 8];
  const u16* pb_ = &wsel[(size_t)(col0 + srow) * ND + ssl * 8];
  u16* la_ = &lA[srow * 64 + dsl * 8];
  u16* lb_ = &lB[srow * 64 + dsl * 8];
  constexpr size_t RSTEP = (size_t)32 * ND;   // 32 rows

  uint4 rA0, rA1, rA2, rA3, rB0, rB1, rB2, rB3;   // named scalars: stay in VGPRs
  auto issue = [&](int k0) {
    rA0 = *(const uint4*)&pa_[k0];
    rA1 = *(const uint4*)&pa_[k0 + RSTEP];
    rA2 = *(const uint4*)&pa_[k0 + 2 * RSTEP];
    rA3 = *(const uint4*)&pa_[k0 + 3 * RSTEP];
    rB0 = *(const uint4*)&pb_[k0];
    rB1 = *(const uint4*)&pb_[k0 + RSTEP];
    rB2 = *(const uint4*)&pb_[k0 + 2 * RSTEP];
    rB3 = *(const uint4*)&pb_[k0 + 3 * RSTEP];
  };
  auto commit = [&]() {
    *(uint4*)&la_[0]         = rA0;
    *(uint4*)&la_[32 * 64]   = rA1;
    *(uint4*)&la_[64 * 64]   = rA2;
    *(uint4*)&la_[96 * 64]   = rA3;
    *(uint4*)&lb_[0]         = rB0;
    *(uint4*)&lb_[32 * 64]   = rB1;
    *(uint4*)&lb_[64 * 64]   = rB2;
    *(uint4*)&lb_[96 * 64]   = rB3;
  };

  f32x4 acc[4][4] = {};

  issue(0);
  commit();
  __syncthreads();

  for (int k0 = 0;;) {
    const int nk = k0 + 64;
    if (nk < ND) issue(nk);        // prefetch in flight under compute below

    short8 a[4][2], b[4][2];
#pragma unroll
    for (int m = 0; m < 4; ++m)
#pragma unroll
      for (int c = 0; c < 2; ++c)
        a[m][c] = *(const short8*)&lA[(wm * 64 + m * 16 + li) * 64 + (((c * 4 + hi) ^ (li & 7)) << 3)];
#pragma unroll
    for (int n = 0; n < 4; ++n)
#pragma unroll
      for (int c = 0; c < 2; ++c)
        b[n][c] = *(const short8*)&lB[(wn * 64 + n * 16 + li) * 64 + (((c * 4 + hi) ^ (li & 7)) << 3)];
    if (z == 2) {
#pragma unroll
      for (int m = 0; m < 4; ++m)
#pragma unroll
        for (int n = 0; n < 4; ++n)
#pragma unroll
          for (int c = 0; c < 2; ++c)
            acc[m][n] = __builtin_amdgcn_mfma_f32_16x16x32_bf16(a[m][c], b[n][c], acc[m][n], 0, 0, 0);
    } else {  // swapped: acc = C^T fragment (row=feature, col=token)
#pragma unroll
      for (int m = 0; m < 4; ++m)
#pragma unroll
        for (int n = 0; n < 4; ++n)
#pragma unroll
          for (int c = 0; c < 2; ++c)
            acc[m][n] = __builtin_amdgcn_mfma_f32_16x16x32_bf16(b[n][c], a[m][c], acc[m][n], 0, 0, 0);
    }

    k0 = nk;
    if (k0 >= ND) break;
    __syncthreads();               // all waves done reading current tile
    commit();                      // write prefetched tile (vmcnt waited here, latency covered)
    __syncthreads();               // tile ready
  }

#pragma unroll
  for (int m = 0; m < 4; ++m)
#pragma unroll
    for (int n = 0; n < 4; ++n) {
      if (z == 2) {
        // normal: row=token(hi*4+rg), col=feature(li). Pack 4 consecutive t.
        int token0 = row0 + wm * 64 + m * 16 + hi * 4;
        int col    = col0 + wn * 64 + n * 16 + li;
        int b_ = token0 >> 11, t0 = token0 & (NT - 1);
        int h_ = col >> 6,     d_ = col & (NHD - 1);
        uint2 w;
        w.x = pk2bf(acc[m][n][0], acc[m][n][1]);
        w.y = pk2bf(acc[m][n][2], acc[m][n][3]);
        *(uint2*)&osel[(((size_t)(b_ * NH + h_)) * NHD + d_) * NT + t0] = w;
      } else {
        // swapped: row=feature(hi*4+rg), col=token(li). Pack 4 consecutive d.
        int token = row0 + wm * 64 + m * 16 + li;
        int feat0 = col0 + wn * 64 + n * 16 + hi * 4;
        int b_ = token >> 11, t_ = token & (NT - 1);
        int h_ = feat0 >> 6,  d0 = feat0 & (NHD - 1);
        uint2 w;
        w.x = pk2bf(acc[m][n][0] * scl, acc[m][n][1] * scl);
        w.y = pk2bf(acc[m][n][2] * scl, acc[m][n][3] * scl);
        *(uint2*)&osel[(((size_t)(b_ * NH + h_)) * NT + t_) * NHD + d0] = w;
      }
    }
}

// ---------------- WO GEMM + residual: out = x + AO @ WO^T (f32 out) ----------------
// Same T14 reg-staged pipeline (named scalars); swapped orientation -> float4 epilogue.
__global__ __launch_bounds__(256, 3) void gemm_wo(
    const u16* __restrict__ ao, const u16* __restrict__ wob,
    const float* __restrict__ x, float* __restrict__ y) {
  const int row0 = blockIdx.x << 7;
  const int col0 = blockIdx.y << 7;

  const int tid  = threadIdx.x;
  const int lane = tid & 63, wid = tid >> 6;
  const int wm = wid >> 1, wn = wid & 1;
  const int li = lane & 15, hi = lane >> 4;

  __shared__ __align__(16) u16 lA[128 * 64];
  __shared__ __align__(16) u16 lB[128 * 64];

  const int srow = tid >> 3;
  const int dsl  = tid & 7;
  const int ssl  = dsl ^ (srow & 7);

  const u16* pa_ = &ao [(size_t)(row0 + srow) * ND + ssl * 8];
  const u16* pb_ = &wob[(size_t)(col0 + srow) * ND + ssl * 8];
  u16* la_ = &lA[srow * 64 + dsl * 8];
  u16* lb_ = &lB[srow * 64 + dsl * 8];
  constexpr size_t RSTEP = (size_t)32 * ND;

  uint4 rA0, rA1, rA2, rA3, rB0, rB1, rB2, rB3;
  auto issue = [&](int k0) {
    rA0 = *(const uint4*)&pa_[k0];
    rA1 = *(const uint4*)&pa_[k0 + RSTEP];
    rA2 = *(const uint4*)&pa_[k0 + 2 * RSTEP];
    rA3 = *(const uint4*)&pa_[k0 + 3 * RSTEP];
    rB0 = *(const uint4*)&pb_[k0];
    rB1 = *(const uint4*)&pb_[k0 + RSTEP];
    rB2 = *(const uint4*)&pb_[k0 + 2 * RSTEP];
    rB3 = *(const uint4*)&pb_[k0 + 3 * RSTEP];
  };
  auto commit = [&]() {
    *(uint4*)&la_[0]         = rA0;
    *(uint4*)&la_[32 * 64]   = rA1;
    *(uint4*)&la_[64 * 64]   = rA2;
    *(uint4*)&la_[96 * 64]   = rA3;
    *(uint4*)&lb_[0]         = rB0;
    *(uint4*)&lb_[32 * 64]   = rB1;
    *(uint4*)&lb_[64 * 64]   = rB2;
    *(uint4*)&lb_[96 * 64]   = rB3;
  };

  f32x4 acc[4][4] = {};

  issue(0);
  commit();
  __syncthreads();

  for (int k0 = 0;;) {
    const int nk = k0 + 64;
    if (nk < ND) issue(nk);

    short8 a[4][2], b[4][2];
#pragma unroll
    for (int m = 0; m < 4; ++m)
#pragma unroll
      for (int c = 0; c < 2; ++c)
        a[m][c] = *(const short8*)&lA[(wm * 64 + m * 16 + li) * 64 + (((c * 4 + hi) ^ (li & 7)) << 3)];
#pragma unroll
    for (int n = 0; n < 4; ++n)
#pragma unroll
      for (int c = 0; c < 2; ++c)
        b[n][c] = *(const short8*)&lB[(wn * 64 + n * 16 + li) * 64 + (((c * 4 + hi) ^ (li & 7)) << 3)];
#pragma unroll
    for (int m = 0; m < 4; ++m)
#pragma unroll
      for (int n = 0; n < 4; ++n)
#pragma unroll
        for (int c = 0; c < 2; ++c)
          acc[m][n] = __builtin_amdgcn_mfma_f32_16x16x32_bf16(b[n][c], a[m][c], acc[m][n], 0, 0, 0);

    k0 = nk;
    if (k0 >= ND) break;
    __syncthreads();
    commit();
    __syncthreads();
  }

#pragma unroll
  for (int m = 0; m < 4; ++m)
#pragma unroll
    for (int n = 0; n < 4; ++n) {
      int token = row0 + wm * 64 + m * 16 + li;
      int feat0 = col0 + wn * 64 + n * 16 + hi * 4;
      size_t idx = (size_t)token * ND + feat0;
      float4 xv = *(const float4*)&x[idx];
      float4 o;
      o.x = acc[m][n][0] + xv.x; o.y = acc[m][n][1] + xv.y;
      o.z = acc[m][n][2] + xv.z; o.w = acc[m][n][3] + xv.w;
      *(float4*)&y[idx] = o;
    }
}

// ---------------- causal flash attention (static-max softmax) ----------------
// grid 2048, XCD-swizzled + heavy-first. 4 waves; wave owns 16 q-rows.
// STATIC-MAX: P = exp2(S) with NO running max / rescale (scores bounded; f32 accum).
__global__ __launch_bounds__(256) void attn_kernel(
    const u16* __restrict__ Q, const u16* __restrict__ K, const u16* __restrict__ VT,
    u16* __restrict__ AO) {
  // T1: XCD-aware swizzle (2048 % 8 == 0 -> bijective)
  const int nb  = gridDim.x * gridDim.y;           // 2048
  const int b0  = blockIdx.y * gridDim.x + blockIdx.x;
  const int L   = (b0 & 7) * (nb >> 3) + (b0 >> 3);
  const int qb  = 31 - (L & 31);     // heavy-first: big qb dispatched early
  const int bh  = L >> 5;            // 0..63

  const int tid = threadIdx.x;
  const int lane = tid & 63, wid = tid >> 6;
  const int li = lane & 15, hi = lane >> 4;
  const int r0 = qb * 64 + wid * 16;         // wave's q rows
  const int qrow = r0 + li;                  // this lane's q row
  const size_t bK = (size_t)bh * NT * NHD;   // K  [bh][t][d]
  const size_t bV = (size_t)bh * NHD * NT;   // VT [bh][d][t]

  __shared__ __align__(16) u16 lK [2][64 * 64];
  __shared__ __align__(16) u16 lVT[2][64 * 64];
  __shared__ __align__(16) u16 lP [4][16 * 64];

  // ---- reg-staging geometry: 512 chunks of 8 u16 per tile; thread owns ch0=tid, ch1=tid+256
  const int ch0 = tid, ch1 = tid + 256;
  const int d0 = (ch0 >> 3) * 64 + (((ch0 & 7) ^ ((ch0 >> 3) & 7)) << 3);
  const int d1 = (ch1 >> 3) * 64 + (((ch1 & 7) ^ ((ch1 >> 3) & 7)) << 3);
  const int vOff0 = (ch0 >> 3) * NT + (ch0 & 7) * 8;
  const int vOff1 = (ch1 >> 3) * NT + (ch1 & 7) * 8;

  uint4 gK0, gK1, gV0, gV1;
  auto issue = [&](int kt) {
    const u16* kp = K + bK + (size_t)kt * 4096;
    const u16* vp = VT + bV + kt * 64;
    gK0 = *(const uint4*)&kp[ch0 * 8];
    gK1 = *(const uint4*)&kp[ch1 * 8];
    gV0 = *(const uint4*)&vp[vOff0];
    gV1 = *(const uint4*)&vp[vOff1];
  };
  auto commit = [&](int buf) {
    *(uint4*)&lK [buf][d0] = gK0;
    *(uint4*)&lK [buf][d1] = gK1;
    *(uint4*)&lVT[buf][d0] = gV0;
    *(uint4*)&lVT[buf][d1] = gV1;
  };

  // Q fragments (B-operand): lane holds Q[qrow][c*32 + hi*8 + e]
  short8 qf[2];
#pragma unroll
  for (int c = 0; c < 2; ++c)
    qf[c] = *(const short8*)&Q[bK + (size_t)qrow * NHD + c * 32 + hi * 8];

  short8 vone;
#pragma unroll
  for (int e = 0; e < 8; ++e) vone[e] = (short)0x3F80;   // bf16 1.0

  f32x4 o[4] = {};
  f32x4 o4 = {};          // rowsum accumulator (all 4 regs equal)

  issue(0);
  commit(0);
  __syncthreads();
  int buf = 0;

  const int pswz = (li & 7) << 1;   // P-LDS XOR swizzle (8B chunks, bit0 preserved)

  for (int kt = 0; kt <= qb; ++kt) {
    if (kt < qb) issue(kt + 1);    // loads in flight under the compute below

    // S^T = K Q^T : s[g][rg] = S[q=li][k = g*16 + hi*4 + rg]
    f32x4 s[4] = {};
    __builtin_amdgcn_s_setprio(1);
#pragma unroll
    for (int g = 0; g < 4; ++g)
#pragma unroll
      for (int c = 0; c < 2; ++c) {
        short8 kf = *(const short8*)&lK[buf][(g * 16 + li) * 64 + ((c * 4 + hi) ^ (li & 7)) * 8];
        s[g] = __builtin_amdgcn_mfma_f32_16x16x32_bf16(kf, qf[c], s[g], 0, 0, 0);
      }
    __builtin_amdgcn_s_setprio(0);

    if (kt == qb) {                          // causal mask on diagonal tile
#pragma unroll
      for (int g = 0; g < 4; ++g)
#pragma unroll
        for (int rg = 0; rg < 4; ++rg) {
          int kcol = kt * 64 + g * 16 + hi * 4 + rg;
          if (kcol > qrow) s[g][rg] = -INFINITY;
        }
    }

    // P = exp2(S) -> LDS as bf16 (static-max; exp2(-inf)=0 handles the mask)
#pragma unroll
    for (int g = 0; g < 4; ++g) {
      float p0 = __builtin_amdgcn_exp2f(s[g][0]);
      float p1 = __builtin_amdgcn_exp2f(s[g][1]);
      float p2 = __builtin_amdgcn_exp2f(s[g][2]);
      float p3 = __builtin_amdgcn_exp2f(s[g][3]);
      uint2 w;
      w.x = pk2bf(p0, p1);
      w.y = pk2bf(p2, p3);
      int k8s = (g * 4 + hi) ^ pswz;
      *(uint2*)&lP[wid][li * 64 + k8s * 4] = w;
    }

    // P as B-operand: lane reads P[q=li][c*32 + hi*8 .. +7]
    short8 pa[2];
#pragma unroll
    for (int c = 0; c < 2; ++c)
      pa[c] = *(const short8*)&lP[wid][li * 64 + ((c * 8 + hi * 2) ^ pswz) * 4];

    // O^T += V^T P^T ; rowsum via ones
    __builtin_amdgcn_s_setprio(1);
#pragma unroll
    for (int gd = 0; gd < 4; ++gd)
#pragma unroll
      for (int c = 0; c < 2; ++c) {
        short8 vf = *(const short8*)&lVT[buf][(gd * 16 + li) * 64 + ((c * 4 + hi) ^ (li & 7)) * 8];
        o[gd] = __builtin_amdgcn_mfma_f32_16x16x32_bf16(vf, pa[c], o[gd], 0, 0, 0);
      }
#pragma unroll
    for (int c = 0; c < 2; ++c)
      o4 = __builtin_amdgcn_mfma_f32_16x16x32_bf16(vone, pa[c], o4, 0, 0, 0);
    __builtin_amdgcn_s_setprio(0);

    if (kt < qb) commit(buf ^ 1);   // vmcnt consumed here (hidden under compute above)
    __syncthreads();                // vmcnt already 0 -> no drain stall
    buf ^= 1;
  }

  // epilogue: O /= rowsum; pack 4 bf16 (8B) per gd and store
  const int b_ = bh >> 4, h_ = bh & 15;
  const float inv = 1.0f / o4[0];
  const size_t rowbase = ((size_t)(b_ * NT + qrow)) * ND + h_ * 64;
#pragma unroll
  for (int gd = 0; gd < 4; ++gd) {
    uint2 w;
    w.x = pk2bf(o[gd][0] * inv, o[gd][1] * inv);
    w.y = pk2bf(o[gd][2] * inv, o[gd][3] * inv);
    *(uint2*)&AO[rowbase + gd * 16 + hi * 4] = w;
  }
}

// ---------------- RMSNorm in-place on d_out ----------------
__global__ __launch_bounds__(256) void rmsnorm_kernel(float* __restrict__ y,
                                                      const float* __restrict__ g) {
  const int row = blockIdx.x;
  const int tid = threadIdx.x;
  const int lane = tid & 63, wid = tid >> 6;
  float4 v = ((const float4*)(y + (size_t)row * ND))[tid];
  float ss = v.x * v.x + v.y * v.y + v.z * v.z + v.w * v.w;
#pragma unroll
  for (int off = 32; off; off >>= 1) ss += __shfl_down(ss, off);
  __shared__ float red[4];
  if (lane == 0) red[wid] = ss;
  __syncthreads();
  float tot = red[0] + red[1] + red[2] + red[3];
  float inv = rsqrtf(tot * (1.0f / (float)ND) + 1e-6f);
  float4 gg = ((const float4*)g)[tid];
  float4 o;
  o.x = v.x * inv * gg.x; o.y = v.y * inv * gg.y;
  o.z = v.z * inv * gg.z; o.w = v.w * inv * gg.w;
  ((float4*)(y + (size_t)row * ND))[tid] = o;
}

extern "C" void kernel_launch(void* const* d_in, const int* in_sizes, int n_in,
                              void* d_out, int out_size, void* d_ws, size_t ws_size,
                              hipStream_t stream) {
  const float* x  = (const float*)d_in[0];
  const float* wq = (const float*)d_in[1];
  const float* wk = (const float*)d_in[2];
  const float* wv = (const float*)d_in[3];
  const float* wo = (const float*)d_in[4];
  const float* ng = (const float*)d_in[5];
  float* out = (float*)d_out;

  char* ws = (char*)d_ws;
  u16* xb  = (u16*)(ws);                    // 16 MB  [M, D] bf16
  u16* wqb = (u16*)(ws + (16u << 20));      //  2 MB
  u16* wkb = (u16*)(ws + (18u << 20));
  u16* wvb = (u16*)(ws + (20u << 20));
  u16* wob = (u16*)(ws + (22u << 20));
  u16* Qb  = (u16*)(ws + (24u << 20));      // 16 MB  [B,H,T,HD]
  u16* Kb  = (u16*)(ws + (40u << 20));      // 16 MB  [B,H,T,HD]
  u16* VTb = (u16*)(ws + (56u << 20));      // 16 MB  [B,H,HD,T]  (transposed V)
  u16* AO  = (u16*)(ws + (72u << 20));      // 16 MB  [M, D]  (ends at 88 MB)

  cast_kernel<<<NM * ND / 4 / 256, 256, 0, stream>>>(x, xb, NM * ND / 4);
  cast4_kernel<<<4 * 1024, 256, 0, stream>>>(wq, wk, wv, wo, wqb, wkb, wvb, wob);

  gemm_qkv<<<dim3(64, 8, 3), 256, 0, stream>>>(xb, wqb, wkb, wvb, Qb, Kb, VTb);
  attn_kernel<<<dim3(NT / 64, NB * NH), 256, 0, stream>>>(Qb, Kb, VTb, AO);
  gemm_wo<<<dim3(64, 8), 256, 0, stream>>>(AO, wob, x, out);
  rmsnorm_kernel<<<NM, 256, 0, stream>>>(out, ng);
}

// Round 11
// 206.140 us; speedup vs baseline: 3.9473x; 3.1860x over previous
//
#include <hip/hip_runtime.h>
#include <hip/hip_bf16.h>

// Problem constants (B=4, T=2048, D=1024, H=16, HD=64)
constexpr int NB  = 4;
constexpr int NT  = 2048;
constexpr int ND  = 1024;
constexpr int NH  = 16;
constexpr int NHD = 64;
constexpr int NM  = NB * NT;   // 8192 tokens

typedef unsigned short u16;
typedef __attribute__((ext_vector_type(8))) short  short8;  // 8 bf16 (4 VGPRs)
typedef __attribute__((ext_vector_type(4))) float  f32x4;   // MFMA acc

__device__ __forceinline__ u16 f2bf(float f) {
  unsigned u = __builtin_bit_cast(unsigned, f);
  u += 0x7FFFu + ((u >> 16) & 1u);   // round-to-nearest-even
  return (u16)(u >> 16);
}

// pack two f32 -> 2x bf16 in one dword (compiler emits v_cvt_pk_bf16_f32)
__device__ __forceinline__ unsigned pk2bf(float lo, float hi_) {
  float2 t; t.x = lo; t.y = hi_;
  __hip_bfloat162 h2 = __float22bfloat162_rn(t);
  unsigned u;
  __builtin_memcpy(&u, &h2, 4);
  return u;
}

// async global->LDS, 16B per lane. dst must be wave-uniform; lane i lands at dst + i*16B.
__device__ __forceinline__ void gll16(const u16* src, u16* dst) {
  __builtin_amdgcn_global_load_lds(
      (const __attribute__((address_space(1))) void*)src,
      (__attribute__((address_space(3))) void*)dst, 16, 0, 0);
}

// ---------------- cast f32 -> bf16, vectorized x4 ----------------
__global__ __launch_bounds__(256) void cast_kernel(const float* __restrict__ in,
                                                   u16* __restrict__ out, int n4) {
  int i = blockIdx.x * 256 + threadIdx.x;
  if (i >= n4) return;
  float4 v = ((const float4*)in)[i];
  ushort4 o;
  o.x = f2bf(v.x); o.y = f2bf(v.y); o.z = f2bf(v.z); o.w = f2bf(v.w);
  ((ushort4*)out)[i] = o;
}

// cast all 4 weight matrices in one launch (1024 blocks each)
__global__ __launch_bounds__(256) void cast4_kernel(
    const float* __restrict__ w0, const float* __restrict__ w1,
    const float* __restrict__ w2, const float* __restrict__ w3,
    u16* __restrict__ o0, u16* __restrict__ o1,
    u16* __restrict__ o2, u16* __restrict__ o3) {
  const int z = blockIdx.x >> 10;
  const float* in = (z == 0) ? w0 : (z == 1) ? w1 : (z == 2) ? w2 : w3;
  u16* out       = (z == 0) ? o0 : (z == 1) ? o1 : (z == 2) ? o2 : o3;
  int i = (blockIdx.x & 1023) * 256 + threadIdx.x;
  float4 v = ((const float4*)in)[i];
  ushort4 o;
  o.x = f2bf(v.x); o.y = f2bf(v.y); o.z = f2bf(v.z); o.w = f2bf(v.w);
  ((ushort4*)out)[i] = o;
}

// ---------------- QKV GEMM: y = x @ W^T ----------------
// BK=64 tiles ([128][64] u16, XOR chunk-swizzle = conflict-free, r7: 0 conflicts).
// DOUBLE-BUFFERED global_load_lds: issue tile k+1 into buf^1 at top of iter,
// compute tile k from buf, one barrier at the end -> loads have the whole
// frag-read+MFMA window in flight, with ZERO VGPR involvement (r9/r10 lesson:
// reg-staging spills to scratch under 4x4-acc pressure -> GBs of TCC traffic).
// NATURAL grid mapping (r6: 49 MB fetch vs 200 MB with chunked remap).
__global__ __launch_bounds__(256) void gemm_qkv(
    const u16* __restrict__ xb,
    const u16* __restrict__ wqb, const u16* __restrict__ wkb, const u16* __restrict__ wvb,
    u16* __restrict__ Qb, u16* __restrict__ Kb, u16* __restrict__ VTb) {
  const int z    = blockIdx.z;
  const int row0 = blockIdx.x << 7;
  const int col0 = blockIdx.y << 7;

  const u16* wsel = (z == 0) ? wqb : (z == 1) ? wkb : wvb;
  u16* osel      = (z == 0) ? Qb  : (z == 1) ? Kb  : VTb;
  // attention scale + log2(e) folded into Q (softmax done in exp2 domain)
  const float scl = (z == 0) ? 0.125f * 1.44269504f : 1.0f;

  const int tid  = threadIdx.x;
  const int lane = tid & 63, wid = tid >> 6;
  const int wm = wid >> 1, wn = wid & 1;
  const int li = lane & 15, hi = lane >> 4;
  const int rl8 = lane >> 3, sl = lane & 7;

  __shared__ __align__(16) u16 lA[2][128 * 64];
  __shared__ __align__(16) u16 lB[2][128 * 64];

  // stage tile at k0 into buffer bf: wave wid covers rows wid*32+h*8..+7
  auto stage = [&](int bf, int k0) {
#pragma unroll
    for (int h = 0; h < 4; ++h) {
      int r  = wid * 32 + h * 8 + rl8;
      int cs = ((sl ^ (r & 7)) << 3);
      gll16(&xb  [(size_t)(row0 + r) * ND + k0 + cs], &lA[bf][(wid * 32 + h * 8) * 64]);
      gll16(&wsel[(size_t)(col0 + r) * ND + k0 + cs], &lB[bf][(wid * 32 + h * 8) * 64]);
    }
  };

  f32x4 acc[4][4] = {};

  stage(0, 0);
  __syncthreads();
  int buf = 0;

  for (int k0 = 0; k0 < ND; k0 += 64) {
    if (k0 + 64 < ND) stage(buf ^ 1, k0 + 64);   // loads in flight under compute

    short8 a[4][2], b[4][2];
#pragma unroll
    for (int m = 0; m < 4; ++m)
#pragma unroll
      for (int c = 0; c < 2; ++c)
        a[m][c] = *(const short8*)&lA[buf][(wm * 64 + m * 16 + li) * 64 + (((c * 4 + hi) ^ (li & 7)) << 3)];
#pragma unroll
    for (int n = 0; n < 4; ++n)
#pragma unroll
      for (int c = 0; c < 2; ++c)
        b[n][c] = *(const short8*)&lB[buf][(wn * 64 + n * 16 + li) * 64 + (((c * 4 + hi) ^ (li & 7)) << 3)];
    if (z == 2) {
#pragma unroll
      for (int m = 0; m < 4; ++m)
#pragma unroll
        for (int n = 0; n < 4; ++n)
#pragma unroll
          for (int c = 0; c < 2; ++c)
            acc[m][n] = __builtin_amdgcn_mfma_f32_16x16x32_bf16(a[m][c], b[n][c], acc[m][n], 0, 0, 0);
    } else {  // swapped: acc = C^T fragment (row=feature, col=token)
#pragma unroll
      for (int m = 0; m < 4; ++m)
#pragma unroll
        for (int n = 0; n < 4; ++n)
#pragma unroll
          for (int c = 0; c < 2; ++c)
            acc[m][n] = __builtin_amdgcn_mfma_f32_16x16x32_bf16(b[n][c], a[m][c], acc[m][n], 0, 0, 0);
    }

    __syncthreads();   // drains the prefetch (mostly complete) + guards buf reuse
    buf ^= 1;
  }

#pragma unroll
  for (int m = 0; m < 4; ++m)
#pragma unroll
    for (int n = 0; n < 4; ++n) {
      if (z == 2) {
        // normal: row=token(hi*4+rg), col=feature(li). Pack 4 consecutive t.
        int token0 = row0 + wm * 64 + m * 16 + hi * 4;
        int col    = col0 + wn * 64 + n * 16 + li;
        int b_ = token0 >> 11, t0 = token0 & (NT - 1);
        int h_ = col >> 6,     d_ = col & (NHD - 1);
        uint2 w;
        w.x = pk2bf(acc[m][n][0], acc[m][n][1]);
        w.y = pk2bf(acc[m][n][2], acc[m][n][3]);
        *(uint2*)&osel[(((size_t)(b_ * NH + h_)) * NHD + d_) * NT + t0] = w;
      } else {
        // swapped: row=feature(hi*4+rg), col=token(li). Pack 4 consecutive d.
        int token = row0 + wm * 64 + m * 16 + li;
        int feat0 = col0 + wn * 64 + n * 16 + hi * 4;
        int b_ = token >> 11, t_ = token & (NT - 1);
        int h_ = feat0 >> 6,  d0 = feat0 & (NHD - 1);
        uint2 w;
        w.x = pk2bf(acc[m][n][0] * scl, acc[m][n][1] * scl);
        w.y = pk2bf(acc[m][n][2] * scl, acc[m][n][3] * scl);
        *(uint2*)&osel[(((size_t)(b_ * NH + h_)) * NT + t_) * NHD + d0] = w;
      }
    }
}

// ---------------- WO GEMM + residual: out = x + AO @ WO^T (f32 out) ----------------
// Same double-buffered gll16 structure; swapped orientation -> float4 epilogue.
__global__ __launch_bounds__(256) void gemm_wo(
    const u16* __restrict__ ao, const u16* __restrict__ wob,
    const float* __restrict__ x, float* __restrict__ y) {
  const int row0 = blockIdx.x << 7;
  const int col0 = blockIdx.y << 7;

  const int tid  = threadIdx.x;
  const int lane = tid & 63, wid = tid >> 6;
  const int wm = wid >> 1, wn = wid & 1;
  const int li = lane & 15, hi = lane >> 4;
  const int rl8 = lane >> 3, sl = lane & 7;

  __shared__ __align__(16) u16 lA[2][128 * 64];
  __shared__ __align__(16) u16 lB[2][128 * 64];

  auto stage = [&](int bf, int k0) {
#pragma unroll
    for (int h = 0; h < 4; ++h) {
      int r  = wid * 32 + h * 8 + rl8;
      int cs = ((sl ^ (r & 7)) << 3);
      gll16(&ao [(size_t)(row0 + r) * ND + k0 + cs], &lA[bf][(wid * 32 + h * 8) * 64]);
      gll16(&wob[(size_t)(col0 + r) * ND + k0 + cs], &lB[bf][(wid * 32 + h * 8) * 64]);
    }
  };

  f32x4 acc[4][4] = {};

  stage(0, 0);
  __syncthreads();
  int buf = 0;

  for (int k0 = 0; k0 < ND; k0 += 64) {
    if (k0 + 64 < ND) stage(buf ^ 1, k0 + 64);

    short8 a[4][2], b[4][2];
#pragma unroll
    for (int m = 0; m < 4; ++m)
#pragma unroll
      for (int c = 0; c < 2; ++c)
        a[m][c] = *(const short8*)&lA[buf][(wm * 64 + m * 16 + li) * 64 + (((c * 4 + hi) ^ (li & 7)) << 3)];
#pragma unroll
    for (int n = 0; n < 4; ++n)
#pragma unroll
      for (int c = 0; c < 2; ++c)
        b[n][c] = *(const short8*)&lB[buf][(wn * 64 + n * 16 + li) * 64 + (((c * 4 + hi) ^ (li & 7)) << 3)];
#pragma unroll
    for (int m = 0; m < 4; ++m)
#pragma unroll
      for (int n = 0; n < 4; ++n)
#pragma unroll
        for (int c = 0; c < 2; ++c)
          acc[m][n] = __builtin_amdgcn_mfma_f32_16x16x32_bf16(b[n][c], a[m][c], acc[m][n], 0, 0, 0);

    __syncthreads();
    buf ^= 1;
  }

#pragma unroll
  for (int m = 0; m < 4; ++m)
#pragma unroll
    for (int n = 0; n < 4; ++n) {
      int token = row0 + wm * 64 + m * 16 + li;
      int feat0 = col0 + wn * 64 + n * 16 + hi * 4;
      size_t idx = (size_t)token * ND + feat0;
      float4 xv = *(const float4*)&x[idx];
      float4 o;
      o.x = acc[m][n][0] + xv.x; o.y = acc[m][n][1] + xv.y;
      o.z = acc[m][n][2] + xv.z; o.w = acc[m][n][3] + xv.w;
      *(float4*)&y[idx] = o;
    }
}

// ---------------- causal flash attention (static-max softmax, r10) ----------------
// grid 2048, XCD-swizzled + heavy-first. 4 waves; wave owns 16 q-rows.
// STATIC-MAX: P = exp2(S) with NO running max / rescale (scores bounded; f32 accum).
__global__ __launch_bounds__(256) void attn_kernel(
    const u16* __restrict__ Q, const u16* __restrict__ K, const u16* __restrict__ VT,
    u16* __restrict__ AO) {
  // T1: XCD-aware swizzle (2048 % 8 == 0 -> bijective)
  const int nb  = gridDim.x * gridDim.y;           // 2048
  const int b0  = blockIdx.y * gridDim.x + blockIdx.x;
  const int L   = (b0 & 7) * (nb >> 3) + (b0 >> 3);
  const int qb  = 31 - (L & 31);     // heavy-first: big qb dispatched early
  const int bh  = L >> 5;            // 0..63

  const int tid = threadIdx.x;
  const int lane = tid & 63, wid = tid >> 6;
  const int li = lane & 15, hi = lane >> 4;
  const int r0 = qb * 64 + wid * 16;         // wave's q rows
  const int qrow = r0 + li;                  // this lane's q row
  const size_t bK = (size_t)bh * NT * NHD;   // K  [bh][t][d]
  const size_t bV = (size_t)bh * NHD * NT;   // VT [bh][d][t]

  __shared__ __align__(16) u16 lK [2][64 * 64];
  __shared__ __align__(16) u16 lVT[2][64 * 64];
  __shared__ __align__(16) u16 lP [4][16 * 64];

  // ---- reg-staging geometry: 512 chunks of 8 u16 per tile; thread owns ch0=tid, ch1=tid+256
  const int ch0 = tid, ch1 = tid + 256;
  const int d0 = (ch0 >> 3) * 64 + (((ch0 & 7) ^ ((ch0 >> 3) & 7)) << 3);
  const int d1 = (ch1 >> 3) * 64 + (((ch1 & 7) ^ ((ch1 >> 3) & 7)) << 3);
  const int vOff0 = (ch0 >> 3) * NT + (ch0 & 7) * 8;
  const int vOff1 = (ch1 >> 3) * NT + (ch1 & 7) * 8;

  uint4 gK0, gK1, gV0, gV1;
  auto issue = [&](int kt) {
    const u16* kp = K + bK + (size_t)kt * 4096;
    const u16* vp = VT + bV + kt * 64;
    gK0 = *(const uint4*)&kp[ch0 * 8];
    gK1 = *(const uint4*)&kp[ch1 * 8];
    gV0 = *(const uint4*)&vp[vOff0];
    gV1 = *(const uint4*)&vp[vOff1];
  };
  auto commit = [&](int buf) {
    *(uint4*)&lK [buf][d0] = gK0;
    *(uint4*)&lK [buf][d1] = gK1;
    *(uint4*)&lVT[buf][d0] = gV0;
    *(uint4*)&lVT[buf][d1] = gV1;
  };

  // Q fragments (B-operand): lane holds Q[qrow][c*32 + hi*8 + e]
  short8 qf[2];
#pragma unroll
  for (int c = 0; c < 2; ++c)
    qf[c] = *(const short8*)&Q[bK + (size_t)qrow * NHD + c * 32 + hi * 8];

  short8 vone;
#pragma unroll
  for (int e = 0; e < 8; ++e) vone[e] = (short)0x3F80;   // bf16 1.0

  f32x4 o[4] = {};
  f32x4 o4 = {};          // rowsum accumulator (all 4 regs equal)

  issue(0);
  commit(0);
  __syncthreads();
  int buf = 0;

  const int pswz = (li & 7) << 1;   // P-LDS XOR swizzle (8B chunks, bit0 preserved)

  for (int kt = 0; kt <= qb; ++kt) {
    if (kt < qb) issue(kt + 1);    // loads in flight under the compute below

    // S^T = K Q^T : s[g][rg] = S[q=li][k = g*16 + hi*4 + rg]
    f32x4 s[4] = {};
    __builtin_amdgcn_s_setprio(1);
#pragma unroll
    for (int g = 0; g < 4; ++g)
#pragma unroll
      for (int c = 0; c < 2; ++c) {
        short8 kf = *(const short8*)&lK[buf][(g * 16 + li) * 64 + ((c * 4 + hi) ^ (li & 7)) * 8];
        s[g] = __builtin_amdgcn_mfma_f32_16x16x32_bf16(kf, qf[c], s[g], 0, 0, 0);
      }
    __builtin_amdgcn_s_setprio(0);

    if (kt == qb) {                          // causal mask on diagonal tile
#pragma unroll
      for (int g = 0; g < 4; ++g)
#pragma unroll
        for (int rg = 0; rg < 4; ++rg) {
          int kcol = kt * 64 + g * 16 + hi * 4 + rg;
          if (kcol > qrow) s[g][rg] = -INFINITY;
        }
    }

    // P = exp2(S) -> LDS as bf16 (static-max; exp2(-inf)=0 handles the mask)
#pragma unroll
    for (int g = 0; g < 4; ++g) {
      float p0 = __builtin_amdgcn_exp2f(s[g][0]);
      float p1 = __builtin_amdgcn_exp2f(s[g][1]);
      float p2 = __builtin_amdgcn_exp2f(s[g][2]);
      float p3 = __builtin_amdgcn_exp2f(s[g][3]);
      uint2 w;
      w.x = pk2bf(p0, p1);
      w.y = pk2bf(p2, p3);
      int k8s = (g * 4 + hi) ^ pswz;
      *(uint2*)&lP[wid][li * 64 + k8s * 4] = w;
    }

    // P as B-operand: lane reads P[q=li][c*32 + hi*8 .. +7]
    short8 pa[2];
#pragma unroll
    for (int c = 0; c < 2; ++c)
      pa[c] = *(const short8*)&lP[wid][li * 64 + ((c * 8 + hi * 2) ^ pswz) * 4];

    // O^T += V^T P^T ; rowsum via ones
    __builtin_amdgcn_s_setprio(1);
#pragma unroll
    for (int gd = 0; gd < 4; ++gd)
#pragma unroll
      for (int c = 0; c < 2; ++c) {
        short8 vf = *(const short8*)&lVT[buf][(gd * 16 + li) * 64 + ((c * 4 + hi) ^ (li & 7)) * 8];
        o[gd] = __builtin_amdgcn_mfma_f32_16x16x32_bf16(vf, pa[c], o[gd], 0, 0, 0);
      }
#pragma unroll
    for (int c = 0; c < 2; ++c)
      o4 = __builtin_amdgcn_mfma_f32_16x16x32_bf16(vone, pa[c], o4, 0, 0, 0);
    __builtin_amdgcn_s_setprio(0);

    if (kt < qb) commit(buf ^ 1);   // vmcnt consumed here (hidden under compute above)
    __syncthreads();                // vmcnt already 0 -> no drain stall
    buf ^= 1;
  }

  // epilogue: O /= rowsum; pack 4 bf16 (8B) per gd and store
  const int b_ = bh >> 4, h_ = bh & 15;
  const float inv = 1.0f / o4[0];
  const size_t rowbase = ((size_t)(b_ * NT + qrow)) * ND + h_ * 64;
#pragma unroll
  for (int gd = 0; gd < 4; ++gd) {
    uint2 w;
    w.x = pk2bf(o[gd][0] * inv, o[gd][1] * inv);
    w.y = pk2bf(o[gd][2] * inv, o[gd][3] * inv);
    *(uint2*)&AO[rowbase + gd * 16 + hi * 4] = w;
  }
}

// ---------------- RMSNorm in-place on d_out ----------------
__global__ __launch_bounds__(256) void rmsnorm_kernel(float* __restrict__ y,
                                                      const float* __restrict__ g) {
  const int row = blockIdx.x;
  const int tid = threadIdx.x;
  const int lane = tid & 63, wid = tid >> 6;
  float4 v = ((const float4*)(y + (size_t)row * ND))[tid];
  float ss = v.x * v.x + v.y * v.y + v.z * v.z + v.w * v.w;
#pragma unroll
  for (int off = 32; off; off >>= 1) ss += __shfl_down(ss, off);
  __shared__ float red[4];
  if (lane == 0) red[wid] = ss;
  __syncthreads();
  float tot = red[0] + red[1] + red[2] + red[3];
  float inv = rsqrtf(tot * (1.0f / (float)ND) + 1e-6f);
  float4 gg = ((const float4*)g)[tid];
  float4 o;
  o.x = v.x * inv * gg.x; o.y = v.y * inv * gg.y;
  o.z = v.z * inv * gg.z; o.w = v.w * inv * gg.w;
  ((float4*)(y + (size_t)row * ND))[tid] = o;
}

extern "C" void kernel_launch(void* const* d_in, const int* in_sizes, int n_in,
                              void* d_out, int out_size, void* d_ws, size_t ws_size,
                              hipStream_t stream) {
  const float* x  = (const float*)d_in[0];
  const float* wq = (const float*)d_in[1];
  const float* wk = (const float*)d_in[2];
  const float* wv = (const float*)d_in[3];
  const float* wo = (const float*)d_in[4];
  const float* ng = (const float*)d_in[5];
  float* out = (float*)d_out;

  char* ws = (char*)d_ws;
  u16* xb  = (u16*)(ws);                    // 16 MB  [M, D] bf16
  u16* wqb = (u16*)(ws + (16u << 20));      //  2 MB
  u16* wkb = (u16*)(ws + (18u << 20));
  u16* wvb = (u16*)(ws + (20u << 20));
  u16* wob = (u16*)(ws + (22u << 20));
  u16* Qb  = (u16*)(ws + (24u << 20));      // 16 MB  [B,H,T,HD]
  u16* Kb  = (u16*)(ws + (40u << 20));      // 16 MB  [B,H,T,HD]
  u16* VTb = (u16*)(ws + (56u << 20));      // 16 MB  [B,H,HD,T]  (transposed V)
  u16* AO  = (u16*)(ws + (72u << 20));      // 16 MB  [M, D]  (ends at 88 MB)

  cast_kernel<<<NM * ND / 4 / 256, 256, 0, stream>>>(x, xb, NM * ND / 4);
  cast4_kernel<<<4 * 1024, 256, 0, stream>>>(wq, wk, wv, wo, wqb, wkb, wvb, wob);

  gemm_qkv<<<dim3(64, 8, 3), 256, 0, stream>>>(xb, wqb, wkb, wvb, Qb, Kb, VTb);
  attn_kernel<<<dim3(NT / 64, NB * NH), 256, 0, stream>>>(Qb, Kb, VTb, AO);
  gemm_wo<<<dim3(64, 8), 256, 0, stream>>>(AO, wob, x, out);
  rmsnorm_kernel<<<NM, 256, 0, stream>>>(out, ng);
}